// Round 12
// baseline (936.292 us; speedup 1.0000x reference)
//
#include <hip/hip_runtime.h>
#include <hip/hip_fp16.h>

#define NB 8
#define CAP 128
#define NFEAT 704
#define MSLICE 16           // node slices per (batch,k) in moments
#define PSLICE (MSLICE * 4) // partial slots = slices * subs

// ---------------- setup kernels ----------------

__global__ void count_edges(const int* __restrict__ ei, int E, int* __restrict__ cnt) {
    int e = blockIdx.x * blockDim.x + threadIdx.x;
    if (e < E) atomicAdd(&cnt[ei[E + e]], 1);
}

__global__ void compute_dinv(const int* __restrict__ cnt, float* __restrict__ dinv, int n) {
    int v = blockIdx.x * blockDim.x + threadIdx.x;
    if (v < n) dinv[v] = rsqrtf((float)(cnt[v] + 1));  // +1 self-loop; always > 0
}

// packed edge: low 16 = src node (N < 65536), high 16 = f16 weight
__global__ void fill_edges(const int* __restrict__ ei, int E, const float* __restrict__ dinv,
                           int* __restrict__ cursor, unsigned int* __restrict__ pairs) {
    int e = blockIdx.x * blockDim.x + threadIdx.x;
    if (e < E) {
        int r = ei[e], c = ei[E + e];
        int pos = atomicAdd(&cursor[c], 1);
        if (pos < CAP) {
            float w = dinv[r] * dinv[c];
            __half hw = __float2half_rn(w);
            unsigned short hb = *reinterpret_cast<unsigned short*>(&hw);
            pairs[(size_t)c * CAP + pos] = (unsigned int)(r & 0xFFFF) | ((unsigned int)hb << 16);
        }
    }
}

// pad each node's edge list to a multiple of 8 with zero-weight edges (src 0, w +0)
__global__ void pad_edges(const int* __restrict__ cnt, unsigned int* __restrict__ pairs, int n) {
    int v = blockIdx.x * blockDim.x + threadIdx.x;
    if (v >= n) return;
    int c = min(cnt[v], CAP);
    int c8 = (c + 7) & ~7;
    for (int j = c; j < c8; ++j) pairs[(size_t)v * CAP + j] = 0u;
}

// batch is SORTED: boundaries, no atomics
__global__ void batch_bounds(const int* __restrict__ batch, int n, int* __restrict__ boff) {
    int i = blockIdx.x * blockDim.x + threadIdx.x;
    if (i >= n) return;
    int b = batch[i];
    int pb = (i == 0) ? -1 : batch[i - 1];
    for (int k = pb + 1; k <= b; ++k) boff[k] = i;
    if (i == n - 1) {
        for (int k = b + 1; k <= NB; ++k) boff[k] = n;
    }
}

__global__ void convert_f16(const float* __restrict__ x, unsigned short* __restrict__ xh, int n) {
    int i = blockIdx.x * blockDim.x + threadIdx.x;
    if (i < n) {
        __half h = __float2half_rn(x[i]);
        xh[i] = *reinterpret_cast<unsigned short*>(&h);
    }
}

// ---------------- nontemporal helpers (one-touch f32 streams) ----------

typedef float f32x4 __attribute__((ext_vector_type(4)));

__device__ __forceinline__ float4 ntload_f4(const float* p) {
    f32x4 t = __builtin_nontemporal_load(reinterpret_cast<const f32x4*>(p));
    return make_float4(t.x, t.y, t.z, t.w);
}
__device__ __forceinline__ void ntstore_f4(float* p, float4 v) {
    f32x4 t; t.x = v.x; t.y = v.y; t.z = v.z; t.w = v.w;
    __builtin_nontemporal_store(t, reinterpret_cast<f32x4*>(p));
}

// ---------------- math helpers ----------------

__device__ __forceinline__ float h2f16(unsigned short h) {
    __half hh = *reinterpret_cast<__half*>(&h);
    return __half2float(hh);
}

__device__ __forceinline__ unsigned short f2h_bits(float x) {
    __half h = __float2half_rn(x);
    return *reinterpret_cast<unsigned short*>(&h);
}

__device__ __forceinline__ unsigned int pack2(float a, float b) {
    __half2 p = __float22half2_rn(make_float2(a, b));
    return *reinterpret_cast<unsigned int*>(&p);
}

__device__ __forceinline__ void fma_h4(float w, uint2 m, float* a) {
    float2 f0 = __half22float2(*reinterpret_cast<__half2*>(&m.x));
    float2 f1 = __half22float2(*reinterpret_cast<__half2*>(&m.y));
    a[0] += w * f0.x; a[1] += w * f0.y; a[2] += w * f1.x; a[3] += w * f1.y;
}

__device__ __forceinline__ uint2 pack_h4(float4 v) {
    uint2 r;
    r.x = pack2(v.x, v.y);
    r.y = pack2(v.z, v.w);
    return r;
}

// 4-slot packed row (512 B): half idx = ch*4 + slot; slot0 = L1, slot1+u = L2 unit u
template <int U1>
__device__ __forceinline__ void fma_pk4(float w, uint4 g0, uint4 g1, float a[4][4]) {
    unsigned int lo[4] = {g0.x, g0.z, g1.x, g1.z};   // slots 0,1 per ch
    unsigned int hi[4] = {g0.y, g0.w, g1.y, g1.w};   // slots 2,3 per ch
#pragma unroll
    for (int i = 0; i < 4; ++i) {
        float2 f0 = __half22float2(*reinterpret_cast<__half2*>(&lo[i]));
        float2 f1 = __half22float2(*reinterpret_cast<__half2*>(&hi[i]));
        if (U1) a[0][i] += w * f0.x;
        a[1][i] += w * f0.y;
        a[2][i] += w * f1.x;
        a[3][i] += w * f1.y;
    }
}

// 3-slot packed row (384 B = 3 lines): s01-plane 256 B (half2 (u0,u1) per ch),
// then s2-plane 128 B (u2 per ch). Lane: uint4 @ cg*16 B, uint2 @ 256+cg*8 B.
__device__ __forceinline__ void fma_pk3(float w, uint4 g4, uint2 g2, float a[4][4]) {
    unsigned int q[4] = {g4.x, g4.y, g4.z, g4.w};
#pragma unroll
    for (int i = 0; i < 4; ++i) {
        float2 f = __half22float2(*reinterpret_cast<__half2*>(&q[i]));
        a[1][i] += w * f.x;
        a[2][i] += w * f.y;
    }
    float2 fa = __half22float2(*reinterpret_cast<__half2*>(&g2.x));
    float2 fb = __half22float2(*reinterpret_cast<__half2*>(&g2.y));
    a[3][0] += w * fa.x; a[3][1] += w * fa.y;
    a[3][2] += w * fb.x; a[3][3] += w * fb.y;
}

// edge select from a pair quad by sub phase
__device__ __forceinline__ unsigned int esel(uint4 q, int sub) {
    return sub < 2 ? (sub == 0 ? q.x : q.y) : (sub == 2 ? q.z : q.w);
}

// ---------------- phase A: L1-only steps 1..8 ----------------
// Snap s=1; diffs s=2,4,8 -> S1 slots 0..2 (f32) AND packed pk0 slots 1..3 (f16);
// s=8 state -> pk0 slot 0. Gather loop: 2-stage software pipeline — group k+1's
// pairs+gathers issued BEFORE group k's FMA, so gather latency overlaps compute.

__global__ __launch_bounds__(256) void cascade_A(
    const float* __restrict__ self1, const unsigned short* __restrict__ mir1,
    float* __restrict__ state1o, unsigned short* __restrict__ mir1o,
    float* __restrict__ prev1, int s1,
    const unsigned int* __restrict__ pairs, const int* __restrict__ cnt,
    const float* __restrict__ dinv, int n,
    float* __restrict__ S1, unsigned short* __restrict__ pk0)
{
    int lane = threadIdx.x & 63, widx = threadIdx.x >> 6;
    int node = blockIdx.x * 4 + widx;
    if (node >= n) return;
    node = __builtin_amdgcn_readfirstlane(node);

    int deg = min(cnt[node], CAP);
    int deg8 = (deg + 7) & ~7;
    float dv = dinv[node];
    float selfw = 1.f + dv * dv;

    int sub = lane >> 4;   // edge within group of 4
    int cg  = lane & 15;   // channel quad

    const unsigned int* pb = pairs + (size_t)node * CAP;
    float a[4] = {0.f, 0.f, 0.f, 0.f};

#define LDI_A(J, WA, WB, GA, GB) { \
    uint4 qA_ = *reinterpret_cast<const uint4*>(pb + (J)); \
    uint4 qB_ = *reinterpret_cast<const uint4*>(pb + (J) + 4); \
    unsigned int eA_ = esel(qA_, sub), eB_ = esel(qB_, sub); \
    int sA_ = (int)(eA_ & 0xFFFFu); WA = h2f16((unsigned short)(eA_ >> 16)); \
    int sB_ = (int)(eB_ & 0xFFFFu); WB = h2f16((unsigned short)(eB_ >> 16)); \
    GA = *reinterpret_cast<const uint2*>(mir1 + (size_t)sA_ * 64 + cg * 4); \
    GB = *reinterpret_cast<const uint2*>(mir1 + (size_t)sB_ * 64 + cg * 4); \
}

    if (deg8 > 0) {
        float wA0, wB0, wA1, wB1;
        uint2 xa, xb, ya, yb;
        LDI_A(0, wA0, wB0, xa, xb);
        int j = 0;
        while (true) {
            int j1 = j + 8;
            bool m1 = j1 < deg8;
            if (m1) LDI_A(j1, wA1, wB1, ya, yb);
            fma_h4(wA0, xa, a);
            fma_h4(wB0, xb, a);
            if (!m1) break;
            int j2 = j + 16;
            bool m2 = j2 < deg8;
            if (m2) LDI_A(j2, wA0, wB0, xa, xb);
            fma_h4(wA1, ya, a);
            fma_h4(wB1, yb, a);
            if (!m2) break;
            j = j2;
        }
    }
#undef LDI_A

#pragma unroll
    for (int m = 16; m <= 32; m <<= 1)
#pragma unroll
        for (int k = 0; k < 4; ++k) a[k] += __shfl_xor(a[k], m, 64);

    if (lane < 16) {
        size_t oidx = (size_t)node * 64 + cg * 4;
        float4 hv = ntload_f4(self1 + oidx);
        float4 v;
        v.x = 0.5f * (selfw * hv.x + a[0]);
        v.y = 0.5f * (selfw * hv.y + a[1]);
        v.z = 0.5f * (selfw * hv.z + a[2]);
        v.w = 0.5f * (selfw * hv.w + a[3]);
        ntstore_f4(state1o + oidx, v);
        *reinterpret_cast<uint2*>(mir1o + oidx) = pack_h4(v);
        float* prow = prev1 + oidx;
        if (s1 == 1) {
            ntstore_f4(prow, v);
        } else if (s1 == 2 || s1 == 4 || s1 == 8) {
            float4 pv = ntload_f4(prow);
            ntstore_f4(prow, v);
            float dd[4];
            dd[0] = fabsf(v.x - pv.x); dd[1] = fabsf(v.y - pv.y);
            dd[2] = fabsf(v.z - pv.z); dd[3] = fabsf(v.w - pv.w);
            int slot = (s1 == 2) ? 0 : (s1 == 4) ? 1 : 2;
            float4 d = make_float4(dd[0], dd[1], dd[2], dd[3]);
            ntstore_f4(S1 + (size_t)node * 256 + slot * 64 + cg * 4, d);
            unsigned short* pr = pk0 + (size_t)node * 256 + cg * 16;
#pragma unroll
            for (int i = 0; i < 4; ++i) pr[i * 4 + (slot + 1)] = f2h_bits(dd[i]);
            if (s1 == 8) {
                float vv[4] = {v.x, v.y, v.z, v.w};
#pragma unroll
                for (int i = 0; i < 4; ++i) pr[i * 4 + 0] = f2h_bits(vv[i]);
            }
        }
    }
}

// ---------------- fused cascade on packed rows ----------------
// <1,0,0> phase B f=1..7: 4-slot in/out (slot0 = L1 step s1=f+8).
// <1,0,1> phase B f=8: 4-slot in, 3-slot out (L1 state dead after t=16).
// <0,1,1> phase C s=9..16: 3-slot in/out (384 B rows, no dead bytes).
// Gather loop: 2-stage pipeline (see cascade_A). Pairs cached (4 groups/line);
// one-touch f32 streams nontemporal; pk gathers/stores cached.
// f32 paths identical to the 889-us baseline (same numerics).

template <int U1, int IN3, int OUT3>
__global__ __launch_bounds__(256) void cascade_pk(
    const float* __restrict__ self1, float* __restrict__ state1o,
    float* __restrict__ prev1, int s1,
    const float* __restrict__ self2, int sstride2, long usz2,
    float* __restrict__ state2o, float* __restrict__ prev2, int s2,
    const unsigned short* __restrict__ pkIn, unsigned short* __restrict__ pkOut,
    const unsigned int* __restrict__ pairs, const int* __restrict__ cnt,
    const float* __restrict__ dinv, int n,
    float* __restrict__ S1, float* __restrict__ S2)
{
    int lane = threadIdx.x & 63, widx = threadIdx.x >> 6;
    int node = blockIdx.x * 4 + widx;
    if (node >= n) return;
    node = __builtin_amdgcn_readfirstlane(node);

    int deg = min(cnt[node], CAP);
    int deg8 = (deg + 7) & ~7;
    float dv = dinv[node];
    float selfw = 1.f + dv * dv;

    int sub = lane >> 4;
    int cg  = lane & 15;

    const unsigned int* pb = pairs + (size_t)node * CAP;
    float a[4][4];
#pragma unroll
    for (int s = 0; s < 4; ++s)
#pragma unroll
        for (int k = 0; k < 4; ++k) a[s][k] = 0.f;

#define LDI_P4(J, WA, WB, A0, A1, B0, B1) { \
    uint4 qA_ = *reinterpret_cast<const uint4*>(pb + (J)); \
    uint4 qB_ = *reinterpret_cast<const uint4*>(pb + (J) + 4); \
    unsigned int eA_ = esel(qA_, sub), eB_ = esel(qB_, sub); \
    int sA_ = (int)(eA_ & 0xFFFFu); WA = h2f16((unsigned short)(eA_ >> 16)); \
    int sB_ = (int)(eB_ & 0xFFFFu); WB = h2f16((unsigned short)(eB_ >> 16)); \
    const unsigned short* rA_ = pkIn + (size_t)sA_ * 256 + cg * 16; \
    const unsigned short* rB_ = pkIn + (size_t)sB_ * 256 + cg * 16; \
    A0 = *reinterpret_cast<const uint4*>(rA_); \
    A1 = *reinterpret_cast<const uint4*>(rA_ + 8); \
    B0 = *reinterpret_cast<const uint4*>(rB_); \
    B1 = *reinterpret_cast<const uint4*>(rB_ + 8); \
}

#define LDI_P3(J, WA, WB, A4, A2, B4, B2) { \
    uint4 qA_ = *reinterpret_cast<const uint4*>(pb + (J)); \
    uint4 qB_ = *reinterpret_cast<const uint4*>(pb + (J) + 4); \
    unsigned int eA_ = esel(qA_, sub), eB_ = esel(qB_, sub); \
    int sA_ = (int)(eA_ & 0xFFFFu); WA = h2f16((unsigned short)(eA_ >> 16)); \
    int sB_ = (int)(eB_ & 0xFFFFu); WB = h2f16((unsigned short)(eB_ >> 16)); \
    const unsigned short* rA_ = pkIn + (size_t)sA_ * 192; \
    const unsigned short* rB_ = pkIn + (size_t)sB_ * 192; \
    A4 = *reinterpret_cast<const uint4*>(rA_ + cg * 8); \
    A2 = *reinterpret_cast<const uint2*>(rA_ + 128 + cg * 4); \
    B4 = *reinterpret_cast<const uint4*>(rB_ + cg * 8); \
    B2 = *reinterpret_cast<const uint2*>(rB_ + 128 + cg * 4); \
}

    if (deg8 > 0) {
        if (IN3) {
            float wA0, wB0, wA1, wB1;
            uint4 xa4, xb4, ya4, yb4;
            uint2 xa2, xb2, ya2, yb2;
            LDI_P3(0, wA0, wB0, xa4, xa2, xb4, xb2);
            int j = 0;
            while (true) {
                int j1 = j + 8;
                bool m1 = j1 < deg8;
                if (m1) LDI_P3(j1, wA1, wB1, ya4, ya2, yb4, yb2);
                fma_pk3(wA0, xa4, xa2, a);
                fma_pk3(wB0, xb4, xb2, a);
                if (!m1) break;
                int j2 = j + 16;
                bool m2 = j2 < deg8;
                if (m2) LDI_P3(j2, wA0, wB0, xa4, xa2, xb4, xb2);
                fma_pk3(wA1, ya4, ya2, a);
                fma_pk3(wB1, yb4, yb2, a);
                if (!m2) break;
                j = j2;
            }
        } else {
            float wA0, wB0, wA1, wB1;
            uint4 xa0, xa1, xb0, xb1, ya0, ya1, yb0, yb1;
            LDI_P4(0, wA0, wB0, xa0, xa1, xb0, xb1);
            int j = 0;
            while (true) {
                int j1 = j + 8;
                bool m1 = j1 < deg8;
                if (m1) LDI_P4(j1, wA1, wB1, ya0, ya1, yb0, yb1);
                fma_pk4<U1>(wA0, xa0, xa1, a);
                fma_pk4<U1>(wB0, xb0, xb1, a);
                if (!m1) break;
                int j2 = j + 16;
                bool m2 = j2 < deg8;
                if (m2) LDI_P4(j2, wA0, wB0, xa0, xa1, xb0, xb1);
                fma_pk4<U1>(wA1, ya0, ya1, a);
                fma_pk4<U1>(wB1, yb0, yb1, a);
                if (!m2) break;
                j = j2;
            }
        }
    }
#undef LDI_P4
#undef LDI_P3

#pragma unroll
    for (int m = 16; m <= 32; m <<= 1) {
#pragma unroll
        for (int s = U1 ? 0 : 1; s < 4; ++s)
#pragma unroll
            for (int k = 0; k < 4; ++k) a[s][k] += __shfl_xor(a[s][k], m, 64);
    }

    if (lane < 16) {
        float vout[4][4];
#pragma unroll
        for (int i = 0; i < 4; ++i) vout[0][i] = 0.f;

        if (U1) {
            size_t oidx = (size_t)node * 64 + cg * 4;
            float4 hv = ntload_f4(self1 + oidx);
            float4 v;
            v.x = 0.5f * (selfw * hv.x + a[0][0]);
            v.y = 0.5f * (selfw * hv.y + a[0][1]);
            v.z = 0.5f * (selfw * hv.z + a[0][2]);
            v.w = 0.5f * (selfw * hv.w + a[0][3]);
            ntstore_f4(state1o + oidx, v);
            float* prow = prev1 + oidx;
            if (s1 == 2 || s1 == 4 || s1 == 8 || s1 == 16) {
                float4 pv = ntload_f4(prow);
                ntstore_f4(prow, v);
                float4 d;
                d.x = fabsf(v.x - pv.x); d.y = fabsf(v.y - pv.y);
                d.z = fabsf(v.z - pv.z); d.w = fabsf(v.w - pv.w);
                int slot = (s1 == 2) ? 0 : (s1 == 4) ? 1 : (s1 == 8) ? 2 : 3;
                ntstore_f4(S1 + (size_t)node * 256 + slot * 64 + cg * 4, d);
            }
            vout[0][0] = v.x; vout[0][1] = v.y; vout[0][2] = v.z; vout[0][3] = v.w;
        }

#pragma unroll
        for (int u = 0; u < 3; ++u) {
            const float* srow = self2 + (size_t)u * usz2 + (size_t)node * sstride2 + cg * 4;
            float4 hv = ntload_f4(srow);
            float4 v;
            v.x = 0.5f * (selfw * hv.x + a[1 + u][0]);
            v.y = 0.5f * (selfw * hv.y + a[1 + u][1]);
            v.z = 0.5f * (selfw * hv.z + a[1 + u][2]);
            v.w = 0.5f * (selfw * hv.w + a[1 + u][3]);
            size_t oidx = (size_t)u * n * 64 + (size_t)node * 64 + cg * 4;
            ntstore_f4(state2o + oidx, v);
            int snap = 2 << u;
            float* prow = prev2 + oidx;
            if (s2 == snap) {
                ntstore_f4(prow, v);
            } else if (s2 > snap && (s2 == 4 || s2 == 8 || s2 == 16)) {
                float4 pv = ntload_f4(prow);
                ntstore_f4(prow, v);
                float4 d;
                d.x = fabsf(v.x - pv.x); d.y = fabsf(v.y - pv.y);
                d.z = fabsf(v.z - pv.z); d.w = fabsf(v.w - pv.w);
                int slt;
                if (u == 0)      slt = (s2 == 4) ? 0 : (s2 == 8) ? 1 : 3;
                else if (u == 1) slt = (s2 == 8) ? 2 : 4;
                else             slt = 5;
                ntstore_f4(S2 + (size_t)node * 384 + slt * 64 + cg * 4, d);
            }
            vout[1 + u][0] = v.x; vout[1 + u][1] = v.y;
            vout[1 + u][2] = v.z; vout[1 + u][3] = v.w;
        }

        if (OUT3) {
            unsigned short* po = pkOut + (size_t)node * 192;
            uint4 w4; uint2 w2;
            w4.x = pack2(vout[1][0], vout[2][0]);
            w4.y = pack2(vout[1][1], vout[2][1]);
            w4.z = pack2(vout[1][2], vout[2][2]);
            w4.w = pack2(vout[1][3], vout[2][3]);
            w2.x = pack2(vout[3][0], vout[3][1]);
            w2.y = pack2(vout[3][2], vout[3][3]);
            *reinterpret_cast<uint4*>(po + cg * 8) = w4;
            *reinterpret_cast<uint2*>(po + 128 + cg * 4) = w2;
        } else {
            uint4 w0, w1;
            w0.x = pack2(vout[0][0], vout[1][0]); w0.y = pack2(vout[2][0], vout[3][0]);
            w0.z = pack2(vout[0][1], vout[1][1]); w0.w = pack2(vout[2][1], vout[3][1]);
            w1.x = pack2(vout[0][2], vout[1][2]); w1.y = pack2(vout[2][2], vout[3][2]);
            w1.z = pack2(vout[0][3], vout[1][3]); w1.w = pack2(vout[2][3], vout[3][3]);
            unsigned short* po = pkOut + (size_t)node * 256 + cg * 16;
            *reinterpret_cast<uint4*>(po)     = w0;
            *reinterpret_cast<uint4*>(po + 8) = w1;
        }
    }
}

// ---------------- moments (coalesced two-stage, no atomics) ----------------

__global__ __launch_bounds__(256) void moments_part(
    const float* __restrict__ x, const float* __restrict__ S1,
    const float* __restrict__ S2, const int* __restrict__ boff,
    double* __restrict__ part)
{
    int bid = blockIdx.x;                    // b * (11*MSLICE) + k * MSLICE + slice
    int slice = bid % MSLICE;
    int k = (bid / MSLICE) % 11;
    int b = bid / (11 * MSLICE);
    int c = threadIdx.x & 63, sub = threadIdx.x >> 6;

    const float* base; int stride;
    if (k == 0)      { base = x  + c;                stride = 64;  }
    else if (k <= 4) { base = S1 + (k - 1) * 64 + c; stride = 256; }
    else             { base = S2 + (k - 5) * 64 + c; stride = 384; }

    int s0 = boff[b], s1e = boff[b + 1];
    int cntb = s1e - s0;
    int per = (cntb + MSLICE - 1) / MSLICE;
    int i0 = s0 + slice * per;
    int i1 = min(s1e, i0 + per);

    double a1 = 0, a2 = 0, a3 = 0, a4 = 0;
    for (int i = i0 + sub; i < i1; i += 4) {
        double v = (double)__builtin_nontemporal_load(&base[(size_t)i * stride]);
        double qq = v * v;
        a1 += v; a2 += qq; a3 += qq * v; a4 += qq * qq;
    }
    int f = k * 64 + c;
    double* qp = part + ((((size_t)slice * 4 + sub) * NB + b) * NFEAT + f) * 4;
    qp[0] = a1; qp[1] = a2; qp[2] = a3; qp[3] = a4;
}

__global__ void finalize_k(const double* __restrict__ part, const int* __restrict__ boff,
                           const float* __restrict__ W, float* __restrict__ out) {
    int i = blockIdx.x * blockDim.x + threadIdx.x;
    if (i < NB * NFEAT) {
        int b = i / NFEAT, f = i % NFEAT;
        double s1 = 0, s2 = 0, s3 = 0, s4 = 0;
        for (int s = 0; s < PSLICE; ++s) {
            const double* qp = part + (((size_t)s * NB + b) * NFEAT + f) * 4;
            s1 += qp[0]; s2 += qp[1]; s3 += qp[2]; s4 += qp[3];
        }
        double cn = (double)max(boff[b + 1] - boff[b], 1);
        double mean = s1 / cn;
        double e2 = s2 / cn, e3 = s3 / cn, e4 = s4 / cn;
        double var = e2 - mean * mean;
        double m3 = e3 - 3.0 * mean * e2 + 2.0 * mean * mean * mean;
        double m4 = e4 - 4.0 * mean * e3 + 6.0 * mean * mean * e2 - 3.0 * mean * mean * mean * mean;
        float skew, kurt;
        if (var > 0.0) {
            double vs = var * sqrt(var);
            skew = (float)(m3 / vs);
            kurt = (float)(m4 / (var * var));
        } else {
            skew = 0.f; kurt = -3.f;
        }
        out[b * 2816 + f]        = (float)mean;
        out[b * 2816 + 704 + f]  = (float)var;
        out[b * 2816 + 1408 + f] = skew;
        out[b * 2816 + 2112 + f] = kurt;
    } else if (i < NB * NFEAT + 68) {
        int j = i - NB * NFEAT;
        out[NB * 2816 + j] = W[j];
    }
}

// ---------------- launch ----------------

extern "C" void kernel_launch(void* const* d_in, const int* in_sizes, int n_in,
                              void* d_out, int out_size, void* d_ws, size_t ws_size,
                              hipStream_t stream) {
    const float* x     = (const float*)d_in[0];
    const int*   ei    = (const int*)d_in[1];
    const int*   batch = (const int*)d_in[2];
    const float* W     = (const float*)d_in[3];
    int N = in_sizes[0] / 64;   // 20000
    int E = in_sizes[1] / 2;    // 640000
    float* out = (float*)d_out;

    char* p = (char*)d_ws;
    auto alloc = [&](size_t bytes) { char* r = p; p += (bytes + 255) & ~255ULL; return r; };
    float* dinv  = (float*)alloc((size_t)N * 4);
    int*   cnt   = (int*)alloc((size_t)N * 4);
    int*   cursor= (int*)alloc((size_t)N * 4);
    int*   boff  = (int*)alloc((NB + 1) * 4);
    double* part = (double*)alloc((size_t)PSLICE * NB * NFEAT * 4 * 8);
    unsigned int* pairs = (unsigned int*)alloc((size_t)N * CAP * 4);
    float* S1    = (float*)alloc((size_t)N * 256 * 4);
    float* S2    = (float*)alloc((size_t)N * 384 * 4);
    unsigned short* xh  = (unsigned short*)alloc((size_t)N * 64 * 2);
    float* b1A   = (float*)alloc((size_t)N * 64 * 4);
    float* b1B   = (float*)alloc((size_t)N * 64 * 4);
    unsigned short* h1A = (unsigned short*)alloc((size_t)N * 64 * 2);
    unsigned short* h1B = (unsigned short*)alloc((size_t)N * 64 * 2);
    float* prev1 = (float*)alloc((size_t)N * 64 * 4);
    float* b2A   = (float*)alloc((size_t)3 * N * 64 * 4);
    float* b2B   = (float*)alloc((size_t)3 * N * 64 * 4);
    float* prev2 = (float*)alloc((size_t)3 * N * 64 * 4);
    unsigned short* pk0  = (unsigned short*)alloc((size_t)N * 256 * 2);
    unsigned short* pk1  = (unsigned short*)alloc((size_t)N * 256 * 2);
    unsigned short* pk3A = (unsigned short*)alloc((size_t)N * 192 * 2);
    unsigned short* pk3B = (unsigned short*)alloc((size_t)N * 192 * 2);

    hipMemsetAsync(cnt, 0, (size_t)N * 4, stream);
    hipMemsetAsync(cursor, 0, (size_t)N * 4, stream);

    count_edges<<<(E + 255) / 256, 256, 0, stream>>>(ei, E, cnt);
    compute_dinv<<<(N + 255) / 256, 256, 0, stream>>>(cnt, dinv, N);
    fill_edges<<<(E + 255) / 256, 256, 0, stream>>>(ei, E, dinv, cursor, pairs);
    pad_edges<<<(N + 255) / 256, 256, 0, stream>>>(cnt, pairs, N);
    batch_bounds<<<(N + 255) / 256, 256, 0, stream>>>(batch, N, boff);
    convert_f16<<<(N * 64 + 255) / 256, 256, 0, stream>>>(x, xh, N * 64);

    long nu = (long)N * 64;
    int cgrid = (N + 3) / 4;

    // ---- phase A: L1 steps 1..8 (fills S1 slots 0..2 + packed pk0) ----
    for (int s = 1; s <= 8; ++s) {
        const float* si = (s == 1) ? x  : ((s & 1) ? b1B : b1A);
        const unsigned short* mi = (s == 1) ? xh : ((s & 1) ? h1B : h1A);
        float* so = (s & 1) ? b1A : b1B;
        unsigned short* mo = (s & 1) ? h1A : h1B;
        cascade_A<<<cgrid, 256, 0, stream>>>(
            si, mi, so, mo, prev1, s,
            pairs, cnt, dinv, N, S1, pk0);
    }

    // ---- phase B: fused — L1 step t=f+8 + 3 L2 units step f, packed gathers ----
    for (int f = 1; f <= 8; ++f) {
        int t = f + 8;
        const float* s1i = ((t - 1) & 1) ? b1A : b1B;
        float* s1o = (t & 1) ? b1A : b1B;
        const float* s2i; int sstride2; long usz2;
        if (f == 1) { s2i = S1; sstride2 = 256; usz2 = 64; }
        else        { s2i = ((f - 1) & 1) ? b2A : b2B; sstride2 = 64; usz2 = nu; }
        float* s2o = (f & 1) ? b2A : b2B;
        const unsigned short* pkI = (f & 1) ? pk0 : pk1;
        if (f < 8) {
            unsigned short* pkO = (f & 1) ? pk1 : pk0;
            cascade_pk<1, 0, 0><<<cgrid, 256, 0, stream>>>(
                s1i, s1o, prev1, t,
                s2i, sstride2, usz2, s2o, prev2, f,
                pkI, pkO, pairs, cnt, dinv, N, S1, S2);
        } else {
            cascade_pk<1, 0, 1><<<cgrid, 256, 0, stream>>>(
                s1i, s1o, prev1, t,
                s2i, sstride2, usz2, s2o, prev2, f,
                pkI, pk3A, pairs, cnt, dinv, N, S1, S2);
        }
    }

    // ---- phase C: L2-only steps 9..16 on 3-slot rows (diffs at 16 -> S2 3,4,5) ----
    for (int s = 9; s <= 16; ++s) {
        const float* s2i = ((s - 1) & 1) ? b2A : b2B;
        float* s2o = (s & 1) ? b2A : b2B;
        const unsigned short* pkI = (s & 1) ? pk3A : pk3B;
        unsigned short*       pkO = (s & 1) ? pk3B : pk3A;
        cascade_pk<0, 1, 1><<<cgrid, 256, 0, stream>>>(
            nullptr, nullptr, nullptr, 0,
            s2i, 64, nu, s2o, prev2, s,
            pkI, pkO, pairs, cnt, dinv, N, S1, S2);
    }

    moments_part<<<NB * 11 * MSLICE, 256, 0, stream>>>(x, S1, S2, boff, part);

    int fin_threads = NB * NFEAT + 68;
    finalize_k<<<(fin_threads + 255) / 256, 256, 0, stream>>>(part, boff, W, out);
}

// Round 15
// 896.656 us; speedup vs baseline: 1.0442x; 1.0442x over previous
//
#include <hip/hip_runtime.h>
#include <hip/hip_fp16.h>

#define NB 8
#define CAP 128
#define NFEAT 704
#define MSLICE 16           // node slices per (batch,k) in moments
#define PSLICE (MSLICE * 4) // partial slots = slices * subs

// ---------------- setup kernels ----------------

__global__ void count_edges(const int* __restrict__ ei, int E, int* __restrict__ cnt) {
    int e = blockIdx.x * blockDim.x + threadIdx.x;
    if (e < E) atomicAdd(&cnt[ei[E + e]], 1);
}

__global__ void compute_dinv(const int* __restrict__ cnt, float* __restrict__ dinv, int n) {
    int v = blockIdx.x * blockDim.x + threadIdx.x;
    if (v < n) dinv[v] = rsqrtf((float)(cnt[v] + 1));  // +1 self-loop; always > 0
}

// packed edge: low 16 = src node (N < 65536), high 16 = f16 weight
__global__ void fill_edges(const int* __restrict__ ei, int E, const float* __restrict__ dinv,
                           int* __restrict__ cursor, unsigned int* __restrict__ pairs) {
    int e = blockIdx.x * blockDim.x + threadIdx.x;
    if (e < E) {
        int r = ei[e], c = ei[E + e];
        int pos = atomicAdd(&cursor[c], 1);
        if (pos < CAP) {
            float w = dinv[r] * dinv[c];
            __half hw = __float2half_rn(w);
            unsigned short hb = *reinterpret_cast<unsigned short*>(&hw);
            pairs[(size_t)c * CAP + pos] = (unsigned int)(r & 0xFFFF) | ((unsigned int)hb << 16);
        }
    }
}

// pad each node's edge list to a multiple of 8 with zero-weight edges (src 0, w +0)
__global__ void pad_edges(const int* __restrict__ cnt, unsigned int* __restrict__ pairs, int n) {
    int v = blockIdx.x * blockDim.x + threadIdx.x;
    if (v >= n) return;
    int c = min(cnt[v], CAP);
    int c8 = (c + 7) & ~7;
    for (int j = c; j < c8; ++j) pairs[(size_t)v * CAP + j] = 0u;
}

// batch is SORTED: boundaries, no atomics
__global__ void batch_bounds(const int* __restrict__ batch, int n, int* __restrict__ boff) {
    int i = blockIdx.x * blockDim.x + threadIdx.x;
    if (i >= n) return;
    int b = batch[i];
    int pb = (i == 0) ? -1 : batch[i - 1];
    for (int k = pb + 1; k <= b; ++k) boff[k] = i;
    if (i == n - 1) {
        for (int k = b + 1; k <= NB; ++k) boff[k] = n;
    }
}

__global__ void convert_f16(const float* __restrict__ x, unsigned short* __restrict__ xh, int n) {
    int i = blockIdx.x * blockDim.x + threadIdx.x;
    if (i < n) {
        __half h = __float2half_rn(x[i]);
        xh[i] = *reinterpret_cast<unsigned short*>(&h);
    }
}

// ---------------- cascade (U1 L1-units + U2 L2-units per wave, one wave per node) --------
// h_out = 0.5*((1+dinv^2)*h_in + sum w*h_in[src]); gathers read fp16 MIRRORS
// (128 B/row/unit); self term, state, diffs fp32. Lane l: edge-phase sub=l>>4,
// channel quad cg=l&15 (uint2 = 4 halves/gather). Packed 4 B pairs loaded once
// per wave, shared by all U1+U2 units; next 8-edge pair group PREFETCHED before
// the current group's gathers (breaks pair->gather serial chain).
// L1 snap s=1, diffs {2,4,8,16}->S1 slots 0..3 (+f16 S1h slots 0..2).
// L2 unit u: snap s=2<<u, diffs later {4,8,16}->S2 slots.
// Instantiations: <1,0> L1-only, <1,3> fused (L1 step s1 = s2+8), <0,3> L2-only.

__device__ __forceinline__ float h2f16(unsigned short h) {
    __half hh = *reinterpret_cast<__half*>(&h);
    return __half2float(hh);
}

__device__ __forceinline__ void fma_h4(float w, uint2 m, float* a) {
    float2 f0 = __half22float2(*reinterpret_cast<__half2*>(&m.x));
    float2 f1 = __half22float2(*reinterpret_cast<__half2*>(&m.y));
    a[0] += w * f0.x; a[1] += w * f0.y; a[2] += w * f1.x; a[3] += w * f1.y;
}

__device__ __forceinline__ uint2 pack_h4(float4 v) {
    __half2 p01 = __float22half2_rn(make_float2(v.x, v.y));
    __half2 p23 = __float22half2_rn(make_float2(v.z, v.w));
    uint2 r;
    r.x = *reinterpret_cast<unsigned int*>(&p01);
    r.y = *reinterpret_cast<unsigned int*>(&p23);
    return r;
}

template <int U1, int U2>
__global__ __launch_bounds__(256) void cascade_k(
    const float* __restrict__ self1, const unsigned short* __restrict__ mir1,
    float* __restrict__ state1o, unsigned short* __restrict__ mir1o,
    float* __restrict__ prev1, int s1,
    const float* __restrict__ self2, int sstride2, long usz2,
    const unsigned short* __restrict__ mir2, long musz2,
    float* __restrict__ state2o, unsigned short* __restrict__ mir2o,
    float* __restrict__ prev2, int s2,
    const unsigned int* __restrict__ pairs, const int* __restrict__ cnt,
    const float* __restrict__ dinv, int n,
    float* __restrict__ S1, unsigned short* __restrict__ S1h,
    float* __restrict__ S2)
{
    int lane = threadIdx.x & 63, widx = threadIdx.x >> 6;
    int node = blockIdx.x * 4 + widx;
    if (node >= n) return;
    node = __builtin_amdgcn_readfirstlane(node);

    int deg = min(cnt[node], CAP);
    int deg8 = (deg + 7) & ~7;
    float dv = dinv[node];
    float selfw = 1.f + dv * dv;

    int sub = lane >> 4;   // edge within group of 4
    int cg  = lane & 15;   // channel quad: ch cg*4 .. +3

    const unsigned int* pb = pairs + (size_t)node * CAP;

    float a1[U1 ? U1 : 1][4], a2[U2 ? U2 : 1][4];
#pragma unroll
    for (int u = 0; u < (U1 ? U1 : 1); ++u)
#pragma unroll
        for (int k = 0; k < 4; ++k) a1[u][k] = 0.f;
#pragma unroll
    for (int u = 0; u < (U2 ? U2 : 1); ++u)
#pragma unroll
        for (int k = 0; k < 4; ++k) a2[u][k] = 0.f;

    if (deg8 > 0) {
        uint4 qA = *reinterpret_cast<const uint4*>(pb);
        uint4 qB = *reinterpret_cast<const uint4*>(pb + 4);
        int j = 0;
        while (true) {
            int jn = j + 8;
            bool more = jn < deg8;
            uint4 nA, nB;
            if (more) {  // prefetch next pair group before consuming this one
                nA = *reinterpret_cast<const uint4*>(pb + jn);
                nB = *reinterpret_cast<const uint4*>(pb + jn + 4);
            }
            unsigned int eA = sub < 2 ? (sub == 0 ? qA.x : qA.y) : (sub == 2 ? qA.z : qA.w);
            unsigned int eB = sub < 2 ? (sub == 0 ? qB.x : qB.y) : (sub == 2 ? qB.z : qB.w);
            int   sA = (int)(eA & 0xFFFFu);
            float wA = h2f16((unsigned short)(eA >> 16));
            int   sB = (int)(eB & 0xFFFFu);
            float wB = h2f16((unsigned short)(eB >> 16));
            // issue all gathers, then all FMAs
            uint2 g1A, g1B, g2A[U2 ? U2 : 1], g2B[U2 ? U2 : 1];
            if (U1) {
                g1A = *reinterpret_cast<const uint2*>(mir1 + (size_t)sA * 64 + cg * 4);
                g1B = *reinterpret_cast<const uint2*>(mir1 + (size_t)sB * 64 + cg * 4);
            }
#pragma unroll
            for (int u = 0; u < U2; ++u)
                g2A[u] = *reinterpret_cast<const uint2*>(mir2 + (size_t)u * musz2 + (size_t)sA * 64 + cg * 4);
#pragma unroll
            for (int u = 0; u < U2; ++u)
                g2B[u] = *reinterpret_cast<const uint2*>(mir2 + (size_t)u * musz2 + (size_t)sB * 64 + cg * 4);
            if (U1) { fma_h4(wA, g1A, a1[0]); fma_h4(wB, g1B, a1[0]); }
#pragma unroll
            for (int u = 0; u < U2; ++u) {
                fma_h4(wA, g2A[u], a2[u]);
                fma_h4(wB, g2B[u], a2[u]);
            }
            if (!more) break;
            qA = nA; qB = nB; j = jn;
        }
    }

    // reduce the 4 edge-phases: lanes {cg, cg+16, cg+32, cg+48} share channels
#pragma unroll
    for (int m = 16; m <= 32; m <<= 1) {
#pragma unroll
        for (int u = 0; u < U1; ++u)
#pragma unroll
            for (int k = 0; k < 4; ++k) a1[u][k] += __shfl_xor(a1[u][k], m, 64);
#pragma unroll
        for (int u = 0; u < U2; ++u)
#pragma unroll
            for (int k = 0; k < 4; ++k) a2[u][k] += __shfl_xor(a2[u][k], m, 64);
    }

    if (lane < 16) {
        if (U1) {
            float4 hv = *reinterpret_cast<const float4*>(self1 + (size_t)node * 64 + cg * 4);
            float4 v;
            v.x = 0.5f * (selfw * hv.x + a1[0][0]);
            v.y = 0.5f * (selfw * hv.y + a1[0][1]);
            v.z = 0.5f * (selfw * hv.z + a1[0][2]);
            v.w = 0.5f * (selfw * hv.w + a1[0][3]);
            size_t oidx = (size_t)node * 64 + cg * 4;
            *reinterpret_cast<float4*>(state1o + oidx) = v;
            *reinterpret_cast<uint2*>(mir1o + oidx) = pack_h4(v);
            float* prow = prev1 + oidx;
            if (s1 == 1) {
                *reinterpret_cast<float4*>(prow) = v;
            } else if (s1 == 2 || s1 == 4 || s1 == 8 || s1 == 16) {
                float4 pv = *reinterpret_cast<const float4*>(prow);
                *reinterpret_cast<float4*>(prow) = v;
                float4 d;
                d.x = fabsf(v.x - pv.x); d.y = fabsf(v.y - pv.y);
                d.z = fabsf(v.z - pv.z); d.w = fabsf(v.w - pv.w);
                int slot = (s1 == 2) ? 0 : (s1 == 4) ? 1 : (s1 == 8) ? 2 : 3;
                *reinterpret_cast<float4*>(S1 + (size_t)node * 256 + slot * 64 + cg * 4) = d;
                if (slot < 3)
                    *reinterpret_cast<uint2*>(S1h + (size_t)slot * n * 64 + oidx) = pack_h4(d);
            }
        }
#pragma unroll
        for (int u = 0; u < U2; ++u) {
            const float* srow = self2 + (size_t)u * usz2 + (size_t)node * sstride2 + cg * 4;
            float4 hv = *reinterpret_cast<const float4*>(srow);
            float4 v;
            v.x = 0.5f * (selfw * hv.x + a2[u][0]);
            v.y = 0.5f * (selfw * hv.y + a2[u][1]);
            v.z = 0.5f * (selfw * hv.z + a2[u][2]);
            v.w = 0.5f * (selfw * hv.w + a2[u][3]);
            size_t oidx = (size_t)u * n * 64 + (size_t)node * 64 + cg * 4;
            *reinterpret_cast<float4*>(state2o + oidx) = v;
            *reinterpret_cast<uint2*>(mir2o + oidx) = pack_h4(v);
            int snap = 2 << u;
            float* prow = prev2 + oidx;
            if (s2 == snap) {
                *reinterpret_cast<float4*>(prow) = v;
            } else if (s2 > snap && (s2 == 4 || s2 == 8 || s2 == 16)) {
                float4 pv = *reinterpret_cast<const float4*>(prow);
                *reinterpret_cast<float4*>(prow) = v;
                float4 d;
                d.x = fabsf(v.x - pv.x); d.y = fabsf(v.y - pv.y);
                d.z = fabsf(v.z - pv.z); d.w = fabsf(v.w - pv.w);
                int slt;
                if (u == 0)      slt = (s2 == 4) ? 0 : (s2 == 8) ? 1 : 3;
                else if (u == 1) slt = (s2 == 8) ? 2 : 4;
                else             slt = 5;
                *reinterpret_cast<float4*>(S2 + (size_t)node * 384 + slt * 64 + cg * 4) = d;
            }
        }
    }
}

// ---------------- moments (coalesced two-stage, no atomics) ----------------

__global__ __launch_bounds__(256) void moments_part(
    const float* __restrict__ x, const float* __restrict__ S1,
    const float* __restrict__ S2, const int* __restrict__ boff,
    double* __restrict__ part)
{
    int bid = blockIdx.x;                    // b * (11*MSLICE) + k * MSLICE + slice
    int slice = bid % MSLICE;
    int k = (bid / MSLICE) % 11;
    int b = bid / (11 * MSLICE);
    int c = threadIdx.x & 63, sub = threadIdx.x >> 6;

    const float* base; int stride;
    if (k == 0)      { base = x  + c;                stride = 64;  }
    else if (k <= 4) { base = S1 + (k - 1) * 64 + c; stride = 256; }
    else             { base = S2 + (k - 5) * 64 + c; stride = 384; }

    int s0 = boff[b], s1e = boff[b + 1];
    int cntb = s1e - s0;
    int per = (cntb + MSLICE - 1) / MSLICE;
    int i0 = s0 + slice * per;
    int i1 = min(s1e, i0 + per);

    double a1 = 0, a2 = 0, a3 = 0, a4 = 0;
    for (int i = i0 + sub; i < i1; i += 4) {
        double v = (double)base[(size_t)i * stride];
        double qq = v * v;
        a1 += v; a2 += qq; a3 += qq * v; a4 += qq * qq;
    }
    int f = k * 64 + c;
    double* qp = part + ((((size_t)slice * 4 + sub) * NB + b) * NFEAT + f) * 4;
    qp[0] = a1; qp[1] = a2; qp[2] = a3; qp[3] = a4;
}

__global__ void finalize_k(const double* __restrict__ part, const int* __restrict__ boff,
                           const float* __restrict__ W, float* __restrict__ out) {
    int i = blockIdx.x * blockDim.x + threadIdx.x;
    if (i < NB * NFEAT) {
        int b = i / NFEAT, f = i % NFEAT;
        double s1 = 0, s2 = 0, s3 = 0, s4 = 0;
        for (int s = 0; s < PSLICE; ++s) {
            const double* qp = part + (((size_t)s * NB + b) * NFEAT + f) * 4;
            s1 += qp[0]; s2 += qp[1]; s3 += qp[2]; s4 += qp[3];
        }
        double cn = (double)max(boff[b + 1] - boff[b], 1);
        double mean = s1 / cn;
        double e2 = s2 / cn, e3 = s3 / cn, e4 = s4 / cn;
        double var = e2 - mean * mean;
        double m3 = e3 - 3.0 * mean * e2 + 2.0 * mean * mean * mean;
        double m4 = e4 - 4.0 * mean * e3 + 6.0 * mean * mean * e2 - 3.0 * mean * mean * mean * mean;
        float skew, kurt;
        if (var > 0.0) {
            double vs = var * sqrt(var);
            skew = (float)(m3 / vs);
            kurt = (float)(m4 / (var * var));
        } else {
            skew = 0.f; kurt = -3.f;
        }
        out[b * 2816 + f]        = (float)mean;
        out[b * 2816 + 704 + f]  = (float)var;
        out[b * 2816 + 1408 + f] = skew;
        out[b * 2816 + 2112 + f] = kurt;
    } else if (i < NB * NFEAT + 68) {
        int j = i - NB * NFEAT;
        out[NB * 2816 + j] = W[j];
    }
}

// ---------------- launch ----------------

extern "C" void kernel_launch(void* const* d_in, const int* in_sizes, int n_in,
                              void* d_out, int out_size, void* d_ws, size_t ws_size,
                              hipStream_t stream) {
    const float* x     = (const float*)d_in[0];
    const int*   ei    = (const int*)d_in[1];
    const int*   batch = (const int*)d_in[2];
    const float* W     = (const float*)d_in[3];
    int N = in_sizes[0] / 64;   // 20000
    int E = in_sizes[1] / 2;    // 640000
    float* out = (float*)d_out;

    char* p = (char*)d_ws;
    auto alloc = [&](size_t bytes) { char* r = p; p += (bytes + 255) & ~255ULL; return r; };
    float* dinv  = (float*)alloc((size_t)N * 4);
    int*   cnt   = (int*)alloc((size_t)N * 4);
    int*   cursor= (int*)alloc((size_t)N * 4);
    int*   boff  = (int*)alloc((NB + 1) * 4);
    double* part = (double*)alloc((size_t)PSLICE * NB * NFEAT * 4 * 8);
    unsigned int* pairs = (unsigned int*)alloc((size_t)N * CAP * 4);
    float* S1    = (float*)alloc((size_t)N * 256 * 4);
    float* S2    = (float*)alloc((size_t)N * 384 * 4);
    unsigned short* S1h = (unsigned short*)alloc((size_t)3 * N * 64 * 2);
    unsigned short* xh  = (unsigned short*)alloc((size_t)N * 64 * 2);
    float* b1A   = (float*)alloc((size_t)N * 64 * 4);
    float* b1B   = (float*)alloc((size_t)N * 64 * 4);
    unsigned short* h1A = (unsigned short*)alloc((size_t)N * 64 * 2);
    unsigned short* h1B = (unsigned short*)alloc((size_t)N * 64 * 2);
    float* prev1 = (float*)alloc((size_t)N * 64 * 4);
    float* b2A   = (float*)alloc((size_t)3 * N * 64 * 4);
    float* b2B   = (float*)alloc((size_t)3 * N * 64 * 4);
    unsigned short* h2A = (unsigned short*)alloc((size_t)3 * N * 64 * 2);
    unsigned short* h2B = (unsigned short*)alloc((size_t)3 * N * 64 * 2);
    float* prev2 = (float*)alloc((size_t)3 * N * 64 * 4);

    hipMemsetAsync(cnt, 0, (size_t)N * 4, stream);
    hipMemsetAsync(cursor, 0, (size_t)N * 4, stream);

    count_edges<<<(E + 255) / 256, 256, 0, stream>>>(ei, E, cnt);
    compute_dinv<<<(N + 255) / 256, 256, 0, stream>>>(cnt, dinv, N);
    fill_edges<<<(E + 255) / 256, 256, 0, stream>>>(ei, E, dinv, cursor, pairs);
    pad_edges<<<(N + 255) / 256, 256, 0, stream>>>(cnt, pairs, N);
    batch_bounds<<<(N + 255) / 256, 256, 0, stream>>>(batch, N, boff);
    convert_f16<<<(N * 64 + 255) / 256, 256, 0, stream>>>(x, xh, N * 64);

    long nu = (long)N * 64;
    int cgrid = (N + 3) / 4;

    // ---- phase A: L1 steps 1..8 (snap s=1; diffs s=2,4,8 -> S1 slots 0..2 + S1h) ----
    for (int s = 1; s <= 8; ++s) {
        const float* si = (s == 1) ? x  : ((s & 1) ? b1B : b1A);
        const unsigned short* mi = (s == 1) ? xh : ((s & 1) ? h1B : h1A);
        float* so = (s & 1) ? b1A : b1B;
        unsigned short* mo = (s & 1) ? h1A : h1B;
        cascade_k<1, 0><<<cgrid, 256, 0, stream>>>(
            si, mi, so, mo, prev1, s,
            nullptr, 0, 0, nullptr, 0, nullptr, nullptr, nullptr, 0,
            pairs, cnt, dinv, N, S1, S1h, S2);
    }

    // ---- phase B: fused — L1 step t=f+8 with L2 step f, f=1..8 ----
    for (int f = 1; f <= 8; ++f) {
        int t = f + 8;
        const float* s1i = ((t - 1) & 1) ? b1A : b1B;
        const unsigned short* m1i = ((t - 1) & 1) ? h1A : h1B;
        float* s1o = (t & 1) ? b1A : b1B;
        unsigned short* m1o = (t & 1) ? h1A : h1B;
        const float* s2i; int sstride2; long usz2;
        const unsigned short* m2i; long musz2;
        if (f == 1) { s2i = S1; sstride2 = 256; usz2 = 64; m2i = S1h; musz2 = nu; }
        else {
            s2i = ((f - 1) & 1) ? b2A : b2B; sstride2 = 64; usz2 = nu;
            m2i = ((f - 1) & 1) ? h2A : h2B; musz2 = nu;
        }
        float* s2o = (f & 1) ? b2A : b2B;
        unsigned short* m2o = (f & 1) ? h2A : h2B;
        cascade_k<1, 3><<<cgrid, 256, 0, stream>>>(
            s1i, m1i, s1o, m1o, prev1, t,
            s2i, sstride2, usz2, m2i, musz2, s2o, m2o, prev2, f,
            pairs, cnt, dinv, N, S1, S1h, S2);
    }

    // ---- phase C: L2-only steps 9..16 (diffs at 16 -> S2 slots 3,4,5) ----
    for (int s = 9; s <= 16; ++s) {
        const float* s2i = ((s - 1) & 1) ? b2A : b2B;
        const unsigned short* m2i = ((s - 1) & 1) ? h2A : h2B;
        float* s2o = (s & 1) ? b2A : b2B;
        unsigned short* m2o = (s & 1) ? h2A : h2B;
        cascade_k<0, 3><<<cgrid, 256, 0, stream>>>(
            nullptr, nullptr, nullptr, nullptr, nullptr, 0,
            s2i, 64, nu, m2i, nu, s2o, m2o, prev2, s,
            pairs, cnt, dinv, N, S1, S1h, S2);
    }

    moments_part<<<NB * 11 * MSLICE, 256, 0, stream>>>(x, S1, S2, boff, part);

    int fin_threads = NB * NFEAT + 68;
    finalize_k<<<(fin_threads + 255) / 256, 256, 0, stream>>>(part, boff, W, out);
}